// Round 18
// baseline (112.606 us; speedup 1.0000x reference)
//
#include <hip/hip_runtime.h>
#include <math.h>

// AWLoss closed-form: f = 24 - (0.5/511^2) * sum_c S1_c^2 / S2_c
// S1 = sum wgt*Re(F), S2 = sum wgt*|F|^2 over half-spectrum k1 in [0,511),
// k2 in [0,256), wgt = 1 for k2==0 else 2, F = conj(X)Y / |X|^2
// (1e-9 pre-whitening is < 1e-12 relative to |X|^2 ~ 1e4 -> dropped).
// X = DFT2(pad(target)), Y = DFT2(pad(recon)), pad offset 127.
//
// Round-18 stage2: TLP instead of intra-wave MLP. R6-R17 proved one wave
// cannot pipeline the twiddle stream from HIP source (5 variants, all 42us,
// 3 waves/CU, 64 CUs idle). stage1 does the same work in <10us at 12 waves/CU
// -- occupancy is the knob. New shape: 8-wave block owns (ch,t); x1t slice
// staged to LDS ONCE (global_load_lds, so FETCH stays ~24MB -- R15's mistake
// was per-wave re-reads), waves copy frags to pinned regs, then each wave
// works a 4-kt slice with naive twiddle streaming; 2 waves/SIMD cover waits.

#define NCH 48
#define PADOFF 127
#define TWO_PI_F 6.283185307179586f

typedef float f32x4 __attribute__((ext_vector_type(4)));
typedef short s16x8 __attribute__((ext_vector_type(8)));
typedef unsigned short u16;

typedef __attribute__((address_space(1))) const unsigned char* gas_p;
typedef __attribute__((address_space(3))) unsigned char* las_p;

union frag_u { u16 u[8]; s16x8 v; };

__device__ __forceinline__ u16 f2bf(float f) {
    union { float f; unsigned u; } x; x.f = f;
    unsigned r = x.u + 0x7FFFu + ((x.u >> 16) & 1u);
    return (u16)(r >> 16);
}

#define MFMA16(A, B, C) __builtin_amdgcn_mfma_f32_16x16x32_bf16(A, B, C, 0, 0, 0)

// ---------------- setup: twiddle fragment table + acc zero ----------------
// w2f : fragments [kt(32)][c(2)][kk(8)][lane(64)][j(8)] bf16
//       element: tw((16kt + (l&15)) * (32kk + 8(l>>4) + j + 127) mod 511),
//       c=0 cos, c=1 sin; rows k1>=511 zeroed.
__global__ __launch_bounds__(256) void setup(u16* __restrict__ w2f,
                                             float* __restrict__ sacc) {
    __shared__ float cs[511], sn[511];
    int tid = threadIdx.x;
    for (int i = tid; i < 511; i += 256) {
        float a = -TWO_PI_F * (float)i / 511.0f;
        cs[i] = cosf(a);
        sn[i] = sinf(a);
    }
    __syncthreads();

    int i = blockIdx.x * 256 + tid;      // i < 262144
    int j = i & 7, l = (i >> 3) & 63, kk = (i >> 9) & 7;
    int c = (i >> 12) & 1, kt = i >> 13;
    int k1 = 16 * kt + (l & 15);
    u16 v = 0;
    if (k1 < 511) {
        int n = 32 * kk + 8 * (l >> 4) + j;
        int p = (k1 * (n + PADOFF)) % 511;
        v = f2bf(c ? sn[p] : cs[p]);
    }
    w2f[i] = v;
    if (blockIdx.x == 0 && tid < 2 * NCH) sacc[tid] = 0.0f;
}

// ---------------- stage 1: DFT along W (exact R12 version) ----------------
__global__ __launch_bounds__(256, 2) void stage1(const float* __restrict__ target,
                                                 const float* __restrict__ recon,
                                                 const u16* __restrict__ w2f,
                                                 u16* __restrict__ x1t,
                                                 int c0) {
    int tid = threadIdx.x;
    int w = tid >> 6, l = tid & 63;
    int lm = l & 15, lh = l >> 4;
    int h   = blockIdx.x & 1;
    int q   = (blockIdx.x >> 1) & 3;
    int imgl = blockIdx.x >> 3;          // [0, 2cc)
    int lc = imgl >> 1;
    int tsel = imgl & 1;
    const float* src = (tsel == 0 ? target : recon) + (size_t)(c0 + lc) * 65536;
    int r0 = 64 * q;

    __shared__ u16 lin[16384];           // 32 KiB: [(s*8+kk)*512 + l*8]

    {
        int row = tid >> 2;              // 0..63
        int cg  = tid & 3;
        const float* rp = src + (size_t)(r0 + row) * 256 + cg * 64;
        float4 v[16];
        #pragma unroll
        for (int i = 0; i < 16; ++i) v[i] = *(const float4*)(rp + 4 * i);
        u16 b[64];
        #pragma unroll
        for (int i = 0; i < 16; ++i) {
            b[4*i]   = f2bf(v[i].x); b[4*i+1] = f2bf(v[i].y);
            b[4*i+2] = f2bf(v[i].z); b[4*i+3] = f2bf(v[i].w);
        }
        int s = row >> 4, lmw = row & 15;
        #pragma unroll
        for (int i2 = 0; i2 < 8; ++i2) {
            int col0 = cg * 64 + i2 * 8;
            int kk = col0 >> 5, lhw = (col0 >> 3) & 3;
            u16* dst = &lin[((s * 8 + kk) * 512) + (lhw * 16 + lmw) * 8];
            *(s16x8*)dst = *(const s16x8*)&b[i2 * 8];
        }
    }

    int t0 = 8 * h + 2 * w;
    s16x8 tw00[8], tw01[8], tw10[8], tw11[8];
    {
        const u16* p0 = w2f + (size_t)t0 * 8192 + l * 8;
        const u16* p1 = w2f + (size_t)(t0 + 1) * 8192 + l * 8;
        #pragma unroll
        for (int kk = 0; kk < 8; ++kk) {
            tw00[kk] = *(const s16x8*)(p0 + kk * 512);
            tw01[kk] = *(const s16x8*)(p0 + 4096 + kk * 512);
            tw10[kk] = *(const s16x8*)(p1 + kk * 512);
            tw11[kk] = *(const s16x8*)(p1 + 4096 + kk * 512);
        }
    }
    __syncthreads();

    f32x4 a00[4], a01[4], a10[4], a11[4];
    #pragma unroll
    for (int s = 0; s < 4; ++s) {
        a00[s] = (f32x4){0,0,0,0}; a01[s] = (f32x4){0,0,0,0};
        a10[s] = (f32x4){0,0,0,0}; a11[s] = (f32x4){0,0,0,0};
    }
    #pragma unroll
    for (int kk = 0; kk < 8; ++kk) {
        s16x8 af[4];
        #pragma unroll
        for (int s = 0; s < 4; ++s)
            af[s] = *(const s16x8*)&lin[((s * 8 + kk) * 512) + l * 8];
        #pragma unroll
        for (int s = 0; s < 4; ++s) {
            a00[s] = MFMA16(af[s], tw00[kk], a00[s]);
            a01[s] = MFMA16(af[s], tw01[kk], a01[s]);
            a10[s] = MFMA16(af[s], tw10[kk], a10[s]);
            a11[s] = MFMA16(af[s], tw11[kk], a11[s]);
        }
    }

    u16* chdst = x1t + (size_t)(lc * 4 + tsel * 2) * 65536;
    #pragma unroll
    for (int s = 0; s < 4; ++s) {
        size_t off0 = (size_t)(16 * t0 + lm) * 256 + r0 + 16 * s + 4 * lh;
        size_t off1 = off0 + 4096;
        ushort4 o;
        o.x = f2bf(a00[s][0]); o.y = f2bf(a00[s][1]);
        o.z = f2bf(a00[s][2]); o.w = f2bf(a00[s][3]);
        *(ushort4*)(chdst + off0) = o;
        o.x = f2bf(a01[s][0]); o.y = f2bf(a01[s][1]);
        o.z = f2bf(a01[s][2]); o.w = f2bf(a01[s][3]);
        *(ushort4*)(chdst + 65536 + off0) = o;
        o.x = f2bf(a10[s][0]); o.y = f2bf(a10[s][1]);
        o.z = f2bf(a10[s][2]); o.w = f2bf(a10[s][3]);
        *(ushort4*)(chdst + off1) = o;
        o.x = f2bf(a11[s][0]); o.y = f2bf(a11[s][1]);
        o.z = f2bf(a11[s][2]); o.w = f2bf(a11[s][3]);
        *(ushort4*)(chdst + 65536 + off1) = o;
    }
}

// ---------------- stage 2: 8-wave block (ch,t); frags via LDS once; kt split ----------------
// grid = 16cc blocks x 512 thr. Block stages its 32KB x1t slice to LDS via
// global_load_lds (x1t read ONCE globally); each wave copies frags to pinned
// regs and works kt = 4w..4w+3, streaming twiddles from L2 (TLP hides latency).
__global__ __launch_bounds__(512) void stage2(const u16* __restrict__ x1t,
                                              const u16* __restrict__ w2f,
                                              float* __restrict__ sacc,
                                              int c0, int cc) {
    int tid = threadIdx.x;
    int w = tid >> 6, l = tid & 63;
    int lm = l & 15, lh = l >> 4;
    int lc = blockIdx.x >> 4;
    int t  = blockIdx.x & 15;

    __shared__ u16 fbuf[16384];          // 32 KiB: [(plane*8+kk)*512 + l*8]

    // ---- stage (ch,t) x1t slice once per block: 32 pairs, wave w does 4
    const u16* cb = x1t + (size_t)(4 * lc) * 65536;
    int rowoff = (16 * t + lm) * 256 + 8 * lh;
    #pragma unroll
    for (int q = 0; q < 4; ++q) {
        int pair = w * 4 + q;
        int p = pair >> 3, kk = pair & 7;
        const u16* g = cb + (size_t)p * 65536 + rowoff + 32 * kk;
        __builtin_amdgcn_global_load_lds((gas_p)g, (las_p)&fbuf[pair * 512], 16, 0, 0);
    }
    __syncthreads();

    // ---- each wave copies the frags into pinned registers (one-time)
    s16x8 ar[8], ai[8], br[8], bi[8];
    #pragma unroll
    for (int kk = 0; kk < 8; ++kk) {
        ar[kk] = *(const s16x8*)&fbuf[(0 * 8 + kk) * 512 + l * 8];
        ai[kk] = *(const s16x8*)&fbuf[(1 * 8 + kk) * 512 + l * 8];
        br[kk] = *(const s16x8*)&fbuf[(2 * 8 + kk) * 512 + l * 8];
        bi[kk] = *(const s16x8*)&fbuf[(3 * 8 + kk) * 512 + l * 8];
    }
    #pragma unroll
    for (int kk = 0; kk < 8; ++kk)
        asm volatile("" : "+v"(ar[kk]), "+v"(ai[kk]), "+v"(br[kk]), "+v"(bi[kk]));

    int k2 = 16 * t + lm;
    float wgt = (k2 == 0) ? 1.f : 2.f;
    float s1 = 0.f, s2 = 0.f;

    // ---- wave w handles kt = 4w .. 4w+3, twiddles streamed from L2
    for (int i = 0; i < 4; ++i) {
        int kt = 4 * w + i;
        const u16* wp = w2f + (size_t)kt * 8192 + l * 8;
        f32x4 crr = {0,0,0,0}, cii = {0,0,0,0}, cri = {0,0,0,0}, cir = {0,0,0,0};
        f32x4 drr = {0,0,0,0}, dii = {0,0,0,0}, dri = {0,0,0,0}, dir = {0,0,0,0};
        #pragma unroll
        for (int kk = 0; kk < 8; ++kk) {
            s16x8 wr = *(const s16x8*)(wp + kk * 512);
            s16x8 wi = *(const s16x8*)(wp + 4096 + kk * 512);
            crr = MFMA16(wr, ar[kk], crr);
            cii = MFMA16(wi, ai[kk], cii);
            cri = MFMA16(wr, ai[kk], cri);
            cir = MFMA16(wi, ar[kk], cir);
            drr = MFMA16(wr, br[kk], drr);
            dii = MFMA16(wi, bi[kk], dii);
            dri = MFMA16(wr, bi[kk], dri);
            dir = MFMA16(wi, br[kk], dir);
        }
        #pragma unroll
        for (int r = 0; r < 4; ++r) {
            int k1 = 16 * kt + 4 * lh + r;
            float wg2 = (k1 < 511) ? wgt : 0.f;
            float Xr = crr[r] - cii[r], Xi = cri[r] + cir[r];
            float Yr = drr[r] - dii[r], Yi = dri[r] + dir[r];
            float Pr = Xr * Yr + Xi * Yi;
            float Pi = Xr * Yi - Xi * Yr;
            float Q  = Xr * Xr + Xi * Xi;
            float inv = 1.0f / (Q * Q + 1e-30f);
            s1 += wg2 * Pr * Q * inv;
            s2 += wg2 * (Pr * Pr + Pi * Pi) * inv;
        }
    }

    #pragma unroll
    for (int off = 32; off > 0; off >>= 1) {
        s1 += __shfl_down(s1, off);
        s2 += __shfl_down(s2, off);
    }
    if (l == 0) {
        atomicAdd(&sacc[c0 + lc], s1);
        atomicAdd(&sacc[NCH + c0 + lc], s2);
    }
}

__global__ void finalize(const float* __restrict__ s, float* __restrict__ out) {
    int t = threadIdx.x;
    float v = 0.f;
    if (t < NCH) {
        float s1 = s[t], s2 = s[NCH + t];
        v = (s2 != 0.f) ? (s1 * s1) / s2 : 0.f;
    }
    for (int off = 32; off > 0; off >>= 1) v += __shfl_down(v, off);
    if (t == 0) out[0] = 24.0f - 0.5f * v / 261121.0f;
}

// ---------------- launch ----------------
extern "C" void kernel_launch(void* const* d_in, const int* in_sizes, int n_in,
                              void* d_out, int out_size, void* d_ws, size_t ws_size,
                              hipStream_t stream) {
    const float* recon  = (const float*)d_in[0];
    const float* target = (const float*)d_in[1];
    float* out = (float*)d_out;
    char* ws = (char*)d_ws;

    const size_t OFF_W2F = 0;                        // 524288 B
    const size_t OFF_S   = OFF_W2F + 524288;         // 512 B
    const size_t OFF_X1  = OFF_S + 512;

    u16*   w2f  = (u16*)(ws + OFF_W2F);
    float* sacc = (float*)(ws + OFF_S);
    u16*   x1t  = (u16*)(ws + OFF_X1);

    const size_t perch = 4ull * 65536 * 2;           // 512 KiB per channel
    size_t avail = (ws_size > OFF_X1) ? ws_size - OFF_X1 : 0;
    int chunk = (int)(avail / perch);
    if (chunk > NCH) chunk = NCH;
    if (chunk < 1) chunk = 1;

    setup<<<dim3(1024), dim3(256), 0, stream>>>(w2f, sacc);

    for (int c0 = 0; c0 < NCH; c0 += chunk) {
        int cc = (NCH - c0 < chunk) ? (NCH - c0) : chunk;
        stage1<<<dim3(16 * cc), dim3(256), 0, stream>>>(target, recon, w2f, x1t, c0);
        stage2<<<dim3(16 * cc), dim3(512), 0, stream>>>(x1t, w2f, sacc, c0, cc);
    }
    finalize<<<dim3(1), dim3(64), 0, stream>>>(sacc, out);
}

// Round 19
// 80.448 us; speedup vs baseline: 1.3997x; 1.3997x over previous
//
#include <hip/hip_runtime.h>
#include <math.h>

// AWLoss closed-form: f = 24 - (0.5/511^2) * sum_c S1_c^2 / S2_c
// S1 = sum wgt*Re(F), S2 = sum wgt*|F|^2 over half-spectrum k1 in [0,511),
// k2 in [0,256), wgt = 1 for k2==0 else 2, F = conj(X)Y / |X|^2.
// X = DFT2(pad(target)), Y = DFT2(pad(recon)), pad offset 127.
//
// Round-19 stage2, two new levers:
//  (1) conjugate symmetry: W(511-k1) = conj(W(k1)) -> the 8 MFMA chains for
//      tile k1 yield BOTH k1 and 511-k1 outputs (Xr'=crr+cii, Xi'=cri-cir...).
//      Halves MFMA, table (16 tiles), LDS reads, L2 traffic.
//  (2) wave-private LDS twiddle tiles staged with global_load_lds (fire-and-
//      forget batch issue -- the ONLY issue path the scheduler cannot sink,
//      proven R8/R15) + wave-level vmcnt(0). ZERO barriers in the loop.
// Frags stay register-pinned (waves of a block share (ch,t) -> same frags,
// L2-hot). stage1/finalize = R12; setup shrunk to 16 tiles.

#define NCH 48
#define PADOFF 127
#define TWO_PI_F 6.283185307179586f

typedef float f32x4 __attribute__((ext_vector_type(4)));
typedef short s16x8 __attribute__((ext_vector_type(8)));
typedef unsigned short u16;

typedef __attribute__((address_space(1))) const unsigned char* gas_p;
typedef __attribute__((address_space(3))) unsigned char* las_p;

union frag_u { u16 u[8]; s16x8 v; };

__device__ __forceinline__ u16 f2bf(float f) {
    union { float f; unsigned u; } x; x.f = f;
    unsigned r = x.u + 0x7FFFu + ((x.u >> 16) & 1u);
    return (u16)(r >> 16);
}

#define MFMA16(A, B, C) __builtin_amdgcn_mfma_f32_16x16x32_bf16(A, B, C, 0, 0, 0)

// ---------------- setup: twiddle fragment table (16 tiles) + acc zero ----------------
// w2f : fragments [kt(16)][c(2)][kk(8)][lane(64)][j(8)] bf16
//       element: tw((16kt + (l&15)) * (32kk + 8(l>>4) + j + 127) mod 511),
//       c=0 cos, c=1 sin. k1 = 16kt+(l&15) <= 255 (second half via symmetry).
__global__ __launch_bounds__(256) void setup(u16* __restrict__ w2f,
                                             float* __restrict__ sacc) {
    __shared__ float cs[511], sn[511];
    int tid = threadIdx.x;
    for (int i = tid; i < 511; i += 256) {
        float a = -TWO_PI_F * (float)i / 511.0f;
        cs[i] = cosf(a);
        sn[i] = sinf(a);
    }
    __syncthreads();

    int i = blockIdx.x * 256 + tid;      // i < 131072
    int j = i & 7, l = (i >> 3) & 63, kk = (i >> 9) & 7;
    int c = (i >> 12) & 1, kt = i >> 13;
    int k1 = 16 * kt + (l & 15);
    int n = 32 * kk + 8 * (l >> 4) + j;
    int p = (k1 * (n + PADOFF)) % 511;
    w2f[i] = f2bf(c ? sn[p] : cs[p]);
    if (blockIdx.x == 0 && tid < 2 * NCH) sacc[tid] = 0.0f;
}

// ---------------- stage 1: DFT along W (exact R12 version; uses tiles 0..15) ----------------
__global__ __launch_bounds__(256, 2) void stage1(const float* __restrict__ target,
                                                 const float* __restrict__ recon,
                                                 const u16* __restrict__ w2f,
                                                 u16* __restrict__ x1t,
                                                 int c0) {
    int tid = threadIdx.x;
    int w = tid >> 6, l = tid & 63;
    int lm = l & 15, lh = l >> 4;
    int h   = blockIdx.x & 1;
    int q   = (blockIdx.x >> 1) & 3;
    int imgl = blockIdx.x >> 3;          // [0, 2cc)
    int lc = imgl >> 1;
    int tsel = imgl & 1;
    const float* src = (tsel == 0 ? target : recon) + (size_t)(c0 + lc) * 65536;
    int r0 = 64 * q;

    __shared__ u16 lin[16384];           // 32 KiB: [(s*8+kk)*512 + l*8]

    {
        int row = tid >> 2;              // 0..63
        int cg  = tid & 3;
        const float* rp = src + (size_t)(r0 + row) * 256 + cg * 64;
        float4 v[16];
        #pragma unroll
        for (int i = 0; i < 16; ++i) v[i] = *(const float4*)(rp + 4 * i);
        u16 b[64];
        #pragma unroll
        for (int i = 0; i < 16; ++i) {
            b[4*i]   = f2bf(v[i].x); b[4*i+1] = f2bf(v[i].y);
            b[4*i+2] = f2bf(v[i].z); b[4*i+3] = f2bf(v[i].w);
        }
        int s = row >> 4, lmw = row & 15;
        #pragma unroll
        for (int i2 = 0; i2 < 8; ++i2) {
            int col0 = cg * 64 + i2 * 8;
            int kk = col0 >> 5, lhw = (col0 >> 3) & 3;
            u16* dst = &lin[((s * 8 + kk) * 512) + (lhw * 16 + lmw) * 8];
            *(s16x8*)dst = *(const s16x8*)&b[i2 * 8];
        }
    }

    int t0 = 8 * h + 2 * w;
    s16x8 tw00[8], tw01[8], tw10[8], tw11[8];
    {
        const u16* p0 = w2f + (size_t)t0 * 8192 + l * 8;
        const u16* p1 = w2f + (size_t)(t0 + 1) * 8192 + l * 8;
        #pragma unroll
        for (int kk = 0; kk < 8; ++kk) {
            tw00[kk] = *(const s16x8*)(p0 + kk * 512);
            tw01[kk] = *(const s16x8*)(p0 + 4096 + kk * 512);
            tw10[kk] = *(const s16x8*)(p1 + kk * 512);
            tw11[kk] = *(const s16x8*)(p1 + 4096 + kk * 512);
        }
    }
    __syncthreads();

    f32x4 a00[4], a01[4], a10[4], a11[4];
    #pragma unroll
    for (int s = 0; s < 4; ++s) {
        a00[s] = (f32x4){0,0,0,0}; a01[s] = (f32x4){0,0,0,0};
        a10[s] = (f32x4){0,0,0,0}; a11[s] = (f32x4){0,0,0,0};
    }
    #pragma unroll
    for (int kk = 0; kk < 8; ++kk) {
        s16x8 af[4];
        #pragma unroll
        for (int s = 0; s < 4; ++s)
            af[s] = *(const s16x8*)&lin[((s * 8 + kk) * 512) + l * 8];
        #pragma unroll
        for (int s = 0; s < 4; ++s) {
            a00[s] = MFMA16(af[s], tw00[kk], a00[s]);
            a01[s] = MFMA16(af[s], tw01[kk], a01[s]);
            a10[s] = MFMA16(af[s], tw10[kk], a10[s]);
            a11[s] = MFMA16(af[s], tw11[kk], a11[s]);
        }
    }

    u16* chdst = x1t + (size_t)(lc * 4 + tsel * 2) * 65536;
    #pragma unroll
    for (int s = 0; s < 4; ++s) {
        size_t off0 = (size_t)(16 * t0 + lm) * 256 + r0 + 16 * s + 4 * lh;
        size_t off1 = off0 + 4096;
        ushort4 o;
        o.x = f2bf(a00[s][0]); o.y = f2bf(a00[s][1]);
        o.z = f2bf(a00[s][2]); o.w = f2bf(a00[s][3]);
        *(ushort4*)(chdst + off0) = o;
        o.x = f2bf(a01[s][0]); o.y = f2bf(a01[s][1]);
        o.z = f2bf(a01[s][2]); o.w = f2bf(a01[s][3]);
        *(ushort4*)(chdst + 65536 + off0) = o;
        o.x = f2bf(a10[s][0]); o.y = f2bf(a10[s][1]);
        o.z = f2bf(a10[s][2]); o.w = f2bf(a10[s][3]);
        *(ushort4*)(chdst + off1) = o;
        o.x = f2bf(a11[s][0]); o.y = f2bf(a11[s][1]);
        o.z = f2bf(a11[s][2]); o.w = f2bf(a11[s][3]);
        *(ushort4*)(chdst + 65536 + off1) = o;
    }
}

// ---------------- stage 2: symmetry-halved, wave-private LDS tiles, no barriers ----------------
// grid = 16cc blocks x 256 thr; block = (lc, t). Wave w handles kt = 4w+i
// (k1 in [0,256)); each tile also yields k1' = 511-k1. Twiddles staged into
// the wave's PRIVATE 16KB LDS slot via global_load_lds, wave-level vmcnt(0).
__global__ __launch_bounds__(256) void stage2(const u16* __restrict__ x1t,
                                              const u16* __restrict__ w2f,
                                              float* __restrict__ sacc,
                                              int c0, int cc) {
    int tid = threadIdx.x;
    int w = tid >> 6, l = tid & 63;
    int lm = l & 15, lh = l >> 4;
    int lc = blockIdx.x >> 4;
    int t  = blockIdx.x & 15;

    __shared__ u16 tw[4][8192];          // 64 KiB; wave w owns tw[w]

    // frags: this block's (ch, t) slice, register-pinned (identical across
    // waves -> trailing waves hit L1/L2)
    const u16* base = x1t + (size_t)(4 * lc) * 65536;   // planes Xr,Xi,Yr,Yi
    size_t roff = (size_t)(16 * t + lm) * 256 + 8 * lh;
    s16x8 ar[8], ai[8], br[8], bi[8];
    #pragma unroll
    for (int kk = 0; kk < 8; ++kk) {
        size_t off = roff + 32 * kk;
        ar[kk] = *(const s16x8*)(base + off);
        ai[kk] = *(const s16x8*)(base + 65536 + off);
        br[kk] = *(const s16x8*)(base + 131072 + off);
        bi[kk] = *(const s16x8*)(base + 196608 + off);
    }
    #pragma unroll
    for (int kk = 0; kk < 8; ++kk)
        asm volatile("" : "+v"(ar[kk]), "+v"(ai[kk]), "+v"(br[kk]), "+v"(bi[kk]));

    int k2 = 16 * t + lm;
    float wgt = (k2 == 0) ? 1.f : 2.f;
    float s1 = 0.f, s2 = 0.f;
    u16* myt = &tw[w][0];

    #pragma unroll 1
    for (int i = 0; i < 4; ++i) {
        int kt = 4 * w + i;              // 0..15
        // ---- stage own tile: 16 fire-and-forget global_load_lds
        const u16* gt = w2f + (size_t)kt * 8192 + l * 8;
        #pragma unroll
        for (int j = 0; j < 16; ++j)
            __builtin_amdgcn_global_load_lds((gas_p)(gt + j * 512),
                                             (las_p)(myt + j * 512), 16, 0, 0);
        asm volatile("s_waitcnt vmcnt(0)" ::: "memory");

        f32x4 crr = {0,0,0,0}, cii = {0,0,0,0}, cri = {0,0,0,0}, cir = {0,0,0,0};
        f32x4 drr = {0,0,0,0}, dii = {0,0,0,0}, dri = {0,0,0,0}, dir = {0,0,0,0};
        #pragma unroll
        for (int kk = 0; kk < 8; ++kk) {
            s16x8 wr = *(const s16x8*)(myt + kk * 512 + l * 8);
            s16x8 wi = *(const s16x8*)(myt + 4096 + kk * 512 + l * 8);
            crr = MFMA16(wr, ar[kk], crr);
            cii = MFMA16(wi, ai[kk], cii);
            cri = MFMA16(wr, ai[kk], cri);
            cir = MFMA16(wi, ar[kk], cir);
            drr = MFMA16(wr, br[kk], drr);
            dii = MFMA16(wi, bi[kk], dii);
            dri = MFMA16(wr, bi[kk], dri);
            dir = MFMA16(wi, br[kk], dir);
        }
        asm volatile("s_waitcnt lgkmcnt(0)" ::: "memory");  // tile reads done before next stage

        #pragma unroll
        for (int r = 0; r < 4; ++r) {
            int k1 = 16 * kt + 4 * lh + r;           // 0..255
            {   // primary k1
                float Xr = crr[r] - cii[r], Xi = cri[r] + cir[r];
                float Yr = drr[r] - dii[r], Yi = dri[r] + dir[r];
                float Pr = Xr * Yr + Xi * Yi;
                float Pi = Xr * Yi - Xi * Yr;
                float Q  = Xr * Xr + Xi * Xi;
                float inv = 1.0f / (Q * Q + 1e-30f);
                s1 += wgt * Pr * Q * inv;
                s2 += wgt * (Pr * Pr + Pi * Pi) * inv;
            }
            {   // partner 511-k1 (conj twiddle): excluded only for k1==0
                float wgp = (k1 > 0) ? wgt : 0.f;
                float Xr = crr[r] + cii[r], Xi = cri[r] - cir[r];
                float Yr = drr[r] + dii[r], Yi = dri[r] - dir[r];
                float Pr = Xr * Yr + Xi * Yi;
                float Pi = Xr * Yi - Xi * Yr;
                float Q  = Xr * Xr + Xi * Xi;
                float inv = 1.0f / (Q * Q + 1e-30f);
                s1 += wgp * Pr * Q * inv;
                s2 += wgp * (Pr * Pr + Pi * Pi) * inv;
            }
        }
    }

    #pragma unroll
    for (int off = 32; off > 0; off >>= 1) {
        s1 += __shfl_down(s1, off);
        s2 += __shfl_down(s2, off);
    }
    if (l == 0) {
        atomicAdd(&sacc[c0 + lc], s1);
        atomicAdd(&sacc[NCH + c0 + lc], s2);
    }
}

__global__ void finalize(const float* __restrict__ s, float* __restrict__ out) {
    int t = threadIdx.x;
    float v = 0.f;
    if (t < NCH) {
        float s1 = s[t], s2 = s[NCH + t];
        v = (s2 != 0.f) ? (s1 * s1) / s2 : 0.f;
    }
    for (int off = 32; off > 0; off >>= 1) v += __shfl_down(v, off);
    if (t == 0) out[0] = 24.0f - 0.5f * v / 261121.0f;
}

// ---------------- launch ----------------
extern "C" void kernel_launch(void* const* d_in, const int* in_sizes, int n_in,
                              void* d_out, int out_size, void* d_ws, size_t ws_size,
                              hipStream_t stream) {
    const float* recon  = (const float*)d_in[0];
    const float* target = (const float*)d_in[1];
    float* out = (float*)d_out;
    char* ws = (char*)d_ws;

    const size_t OFF_W2F = 0;                        // 262144 B (16 tiles)
    const size_t OFF_S   = OFF_W2F + 262144;         // 512 B
    const size_t OFF_X1  = OFF_S + 512;

    u16*   w2f  = (u16*)(ws + OFF_W2F);
    float* sacc = (float*)(ws + OFF_S);
    u16*   x1t  = (u16*)(ws + OFF_X1);

    const size_t perch = 4ull * 65536 * 2;           // 512 KiB per channel
    size_t avail = (ws_size > OFF_X1) ? ws_size - OFF_X1 : 0;
    int chunk = (int)(avail / perch);
    if (chunk > NCH) chunk = NCH;
    if (chunk < 1) chunk = 1;

    setup<<<dim3(512), dim3(256), 0, stream>>>(w2f, sacc);

    for (int c0 = 0; c0 < NCH; c0 += chunk) {
        int cc = (NCH - c0 < chunk) ? (NCH - c0) : chunk;
        stage1<<<dim3(16 * cc), dim3(256), 0, stream>>>(target, recon, w2f, x1t, c0);
        stage2<<<dim3(16 * cc), dim3(256), 0, stream>>>(x1t, w2f, sacc, c0, cc);
    }
    finalize<<<dim3(1), dim3(64), 0, stream>>>(sacc, out);
}